// Round 4
// baseline (115.476 us; speedup 1.0000x reference)
//
#include <hip/hip_runtime.h>
#include <math.h>

#define BLK 256

// ---------------------------------------------------------------------------
// Rotated-box intersection area via Green's theorem (no polygon clipping):
// area(P∩Q) = 1/2 ∮ (x dy − y dx) over ∂(P∩Q) = Σ P-edge pieces inside Q
// (computed in Q's AAB frame) + Σ Q-edge pieces inside P (computed in P's
// AAB frame, translation-corrected by 1/2·cross(t, R·ΣΔ); rotation leaves
// x dy − y dx invariant).  Each piece is a branchless Liang-Barsky slab clip.
// Empty clips collapse to zero-length pieces contributing exactly 0.
//
// AoS fix: box_preds / reg_targets / anchors are (...,7) fp32 — direct loads
// put lanes 28 B apart (~28 cache lines per wave instruction).  Each block
// stages its 256x7 floats per array with 7 fully-coalesced dword loads into
// LDS, then threads read their 7 floats from LDS (addresses 7*tid+c: stride
// 7 is coprime to 32 banks -> exactly 2 lanes/bank = conflict-free).
// ---------------------------------------------------------------------------

__device__ __forceinline__ void edge_piece(float px, float py, float ex, float ey,
                                           float hx, float hy,
                                           float& area2, float& Dx, float& Dy)
{
    // clip segment p + s*e, s in [0,1], to box [-hx,hx] x [-hy,hy]
    float gx = copysignf(fmaxf(fabsf(ex), 1e-30f), ex);
    float gy = copysignf(fmaxf(fabsf(ey), 1e-30f), ey);
    float rx = __fdividef(1.0f, gx);
    float ry = __fdividef(1.0f, gy);
    float sx0 = (-hx - px) * rx, sx1 = (hx - px) * rx;
    float sy0 = (-hy - py) * ry, sy1 = (hy - py) * ry;
    float smin = fmaxf(fmaxf(fminf(sx0, sx1), fminf(sy0, sy1)), 0.0f);
    float smax = fminf(fminf(fmaxf(sx0, sx1), fmaxf(sy0, sy1)), 1.0f);
    smax = fmaxf(smax, smin);                  // empty -> zero-length at smin
    float ax = fmaf(smin, ex, px), ay = fmaf(smin, ey, py);
    float bx = fmaf(smax, ex, px), by = fmaf(smax, ey, py);
    float ux = bx - ax, uy = by - ay;          // exactly 0 when smin==smax
    area2 += fmaf(ax, uy, -(ay * ux));         // cross(a, b-a) == cross(a,b)
    Dx += ux; Dy += uy;
}

__global__ __launch_bounds__(BLK)
void iou_pred_loss_kernel(const float* __restrict__ iou_preds,
                          const int*   __restrict__ one_hot,
                          const float* __restrict__ weights,
                          const float* __restrict__ anchors,
                          const float* __restrict__ box_preds,
                          const float* __restrict__ reg_targets,
                          float* __restrict__ out,
                          int N, int total)
{
    __shared__ float sBP[7 * BLK];
    __shared__ float sRT[7 * BLK];
    __shared__ float sAN[7 * BLK];

    int tid  = threadIdx.x;
    int row0 = blockIdx.x * BLK;

    // ---- cooperative coalesced staging of the three (...,7) arrays ----
    size_t base_bt = ((size_t)blockIdx.y * N + row0) * 7;
    size_t base_an = (size_t)row0 * 7;
    if (row0 + BLK <= N) {                      // full block: unguarded fast path
#pragma unroll
        for (int k = 0; k < 7; ++k) {
            int off = tid + k * BLK;
            sBP[off] = box_preds[base_bt + off];
            sRT[off] = reg_targets[base_bt + off];
            sAN[off] = anchors[base_an + off];
        }
    } else {
        size_t lim_bt = (size_t)total * 7;
        size_t lim_an = (size_t)N * 7;
#pragma unroll
        for (int k = 0; k < 7; ++k) {
            int off = tid + k * BLK;
            sBP[off] = (base_bt + off < lim_bt) ? box_preds[base_bt + off] : 0.0f;
            sRT[off] = (base_bt + off < lim_bt) ? reg_targets[base_bt + off] : 0.0f;
            sAN[off] = (base_an + off < lim_an) ? anchors[base_an + off] : 0.0f;
        }
    }
    __syncthreads();

    int n_idx = row0 + tid;
    if (n_idx >= N) return;
    int gid = blockIdx.y * N + n_idx;

    // ---- anchor (BEV components) ----
    const float* an = sAN + tid * 7;
    float xa = an[0], ya = an[1], dxa = an[3], dya = an[4], ra = an[6];
    float diag = sqrtf(fmaf(dxa, dxa, dya * dya));

    // ---- decode pred box (P) ----
    const float* bp = sBP + tid * 7;
    float x1  = fmaf(bp[0], diag, xa);
    float y1  = fmaf(bp[1], diag, ya);
    float dx1 = __expf(bp[3]) * dxa;
    float dy1 = __expf(bp[4]) * dya;
    float r1  = bp[6] + ra;

    // ---- decode target box (Q) ----
    const float* rt = sRT + tid * 7;
    float x2  = fmaf(rt[0], diag, xa);
    float y2  = fmaf(rt[1], diag, ya);
    float dx2 = __expf(rt[3]) * dxa;
    float dy2 = __expf(rt[4]) * dya;
    float r2  = rt[6] + ra;

    float a1 = dx1 * dy1;
    float a2 = dx2 * dy2;

    float h1x = 0.5f * dx1, h1y = 0.5f * dy1;
    float h2x = 0.5f * dx2, h2y = 0.5f * dy2;

    // ---- P in Q's frame: p_Q = R(dr)·p_P + t ----
    float c2v = __cosf(r2), s2v = __sinf(r2);
    float dr  = r1 - r2;
    float cd  = __cosf(dr), sd = __sinf(dr);
    float ddx = x1 - x2, ddy = y1 - y2;
    float tx  = fmaf(c2v, ddx,  s2v * ddy);    // R(-r2)·(c1 - c2)
    float ty  = fmaf(-s2v, ddx, c2v * ddy);

    // P corners in Q frame (CCW): t ± u ± v, u = R·(h1x,0), v = R·(0,h1y)
    float ux_ = h1x * cd,  uy_ = h1x * sd;
    float vx_ = -h1y * sd, vy_ = h1y * cd;
    float pX[4], pY[4];
    pX[0] = tx + ux_ + vx_;  pY[0] = ty + uy_ + vy_;
    pX[1] = tx - ux_ + vx_;  pY[1] = ty - uy_ + vy_;
    pX[2] = tx - ux_ - vx_;  pY[2] = ty - uy_ - vy_;
    pX[3] = tx + ux_ - vx_;  pY[3] = ty + uy_ - vy_;

    // Q corners in P frame (CCW): o ± u' ± v', u' = R^T·(h2x,0),
    // v' = R^T·(0,h2y), o = -R^T·t
    float upx = h2x * cd,  upy = -h2x * sd;
    float vpx = h2y * sd,  vpy = h2y * cd;
    float ox  = -(fmaf(cd, tx,  sd * ty));
    float oy  = -(fmaf(-sd, tx, cd * ty));
    float qX[4], qY[4];
    qX[0] = ox + upx + vpx;  qY[0] = oy + upy + vpy;
    qX[1] = ox - upx + vpx;  qY[1] = oy - upy + vpy;
    qX[2] = ox - upx - vpx;  qY[2] = oy - upy - vpy;
    qX[3] = ox + upx - vpx;  qY[3] = oy + upy - vpy;

    // ---- accumulate Green terms ----
    float area2 = 0.0f;
    float dumDx = 0.0f, dumDy = 0.0f;          // P-pieces: displacement unused
#pragma unroll
    for (int i = 0; i < 4; ++i) {
        int j = (i + 1) & 3;
        edge_piece(pX[i], pY[i], pX[j] - pX[i], pY[j] - pY[i],
                   h2x, h2y, area2, dumDx, dumDy);
    }
    float Dx = 0.0f, Dy = 0.0f;                // Q-pieces: need net displacement
#pragma unroll
    for (int i = 0; i < 4; ++i) {
        int j = (i + 1) & 3;
        edge_piece(qX[i], qY[i], qX[j] - qX[i], qY[j] - qY[i],
                   h1x, h1y, area2, Dx, Dy);
    }
    // translation correction: cross(t, R·D)
    float RDx = fmaf(cd, Dx, -(sd * Dy));
    float RDy = fmaf(sd, Dx,   cd * Dy);
    area2 += fmaf(tx, RDy, -(ty * RDx));

    float inter = 0.5f * fabsf(area2);

    // ---- IoU + loss ----
    float uni = fmaxf(a1 + a2 - inter, 1e-6f);
    float iou = __fdividef(inter, uni);

    float target = (one_hot[gid] > 0) ? iou : 0.0f;
    float ip = iou_preds[gid];
    float z  = __fdividef(1.0f, 1.0f + __expf(-ip));   // sigmoid
    float pt = __logf(1.0f + __expf(z)) - z * target;  // logaddexp(0,z) - z*target
    out[gid] = pt * weights[gid];
}

extern "C" void kernel_launch(void* const* d_in, const int* in_sizes, int n_in,
                              void* d_out, int out_size, void* d_ws, size_t ws_size,
                              hipStream_t stream) {
    const float* iou_preds   = (const float*)d_in[0];
    const int*   one_hot     = (const int*)  d_in[1];
    const float* weights     = (const float*)d_in[2];
    const float* anchors     = (const float*)d_in[3];
    const float* box_preds   = (const float*)d_in[4];
    const float* reg_targets = (const float*)d_in[5];
    float* out = (float*)d_out;

    int total = in_sizes[0];       // B*N
    int N     = in_sizes[3] / 7;   // anchor count
    int B     = total / N;

    dim3 grid((N + BLK - 1) / BLK, B);
    iou_pred_loss_kernel<<<grid, dim3(BLK), 0, stream>>>(
        iou_preds, one_hot, weights, anchors, box_preds, reg_targets,
        out, N, total);
}

// Round 5
// 111.630 us; speedup vs baseline: 1.0344x; 1.0344x over previous
//
#include <hip/hip_runtime.h>
#include <math.h>

#define BLK 256

// ---------------------------------------------------------------------------
// Rotated-box intersection area via Green's theorem (no polygon clipping):
// area(P∩Q) = 1/2 ∮ (x dy − y dx) = Σ P-edge pieces clipped to Q's AAB frame
// + Σ Q-edge pieces clipped to P's AAB frame + 1/2·cross(t, R·ΣΔ) translation
// correction (x dy − y dx is rotation-invariant).  Each piece is a branchless
// Liang-Barsky slab clip; empty clips give exactly-zero-length pieces.
//
// Edge structure: a box's 4 edge directions are ±2u, ±2v -> only 2 distinct
// reciprocal pairs per box (rcp(-e) = -rcp(e)); clamp+rcp hoisted out of the
// per-edge code (8 rcp/pair total instead of 16).
// Each thread processes the SAME anchor row for 2 batches: anchor load +
// diag decode amortized, all global loads issued up front for MLP.
// ---------------------------------------------------------------------------

__device__ __forceinline__ float clamp_mag(float x) {
    return copysignf(fmaxf(fabsf(x), 1e-30f), x);
}

// clip segment p + s*e, s in [0,1], to box [-hx,hx] x [-hy,hy]; r = 1/e (pre-clamped)
__device__ __forceinline__ void edge_piece(float px, float py, float ex, float ey,
                                           float rx, float ry, float hx, float hy,
                                           float& area2, float& Dx, float& Dy)
{
    float sx0 = (-hx - px) * rx, sx1 = (hx - px) * rx;
    float sy0 = (-hy - py) * ry, sy1 = (hy - py) * ry;
    float smin = fmaxf(fmaxf(fminf(sx0, sx1), fminf(sy0, sy1)), 0.0f);
    float smax = fminf(fminf(fmaxf(sx0, sx1), fmaxf(sy0, sy1)), 1.0f);
    smax = fmaxf(smax, smin);                  // empty -> zero-length at smin
    float ax = fmaf(smin, ex, px), ay = fmaf(smin, ey, py);
    float bx = fmaf(smax, ex, px), by = fmaf(smax, ey, py);
    float ux = bx - ax, uy = by - ay;          // exactly 0 when smin==smax
    area2 += fmaf(ax, uy, -(ay * ux));         // cross(a, b-a) == cross(a,b)
    Dx += ux; Dy += uy;
}

// Full pair IoU -> loss for one (pred, target) box pair sharing an anchor.
__device__ __forceinline__ float pair_loss(const float bp[5], const float rt[5],
                                           float xa, float ya, float dxa, float dya,
                                           float ra, float diag,
                                           float ip, int oh, float w)
{
    // decode P (pred) / Q (target): fields {x, y, dx, dy, r}
    float x1  = fmaf(bp[0], diag, xa);
    float y1  = fmaf(bp[1], diag, ya);
    float dx1 = __expf(bp[2]) * dxa;
    float dy1 = __expf(bp[3]) * dya;
    float r1  = bp[4] + ra;

    float x2  = fmaf(rt[0], diag, xa);
    float y2  = fmaf(rt[1], diag, ya);
    float dx2 = __expf(rt[2]) * dxa;
    float dy2 = __expf(rt[3]) * dya;
    float r2  = rt[4] + ra;

    float a1 = dx1 * dy1, a2 = dx2 * dy2;
    float h1x = 0.5f * dx1, h1y = 0.5f * dy1;
    float h2x = 0.5f * dx2, h2y = 0.5f * dy2;

    // P in Q's frame: p_Q = R(dr)·p_P + t
    float c2v = __cosf(r2), s2v = __sinf(r2);
    float dr  = r1 - r2;
    float cd  = __cosf(dr), sd = __sinf(dr);
    float ddx = x1 - x2, ddy = y1 - y2;
    float tx  = fmaf(c2v, ddx,  s2v * ddy);
    float ty  = fmaf(-s2v, ddx, c2v * ddy);

    // P half-edge vectors in Q frame
    float ux_ = h1x * cd,  uy_ = h1x * sd;
    float vx_ = -h1y * sd, vy_ = h1y * cd;
    // full edge vectors ±2u, ±2v and their shared reciprocals
    float eux = 2.0f * ux_, euy = 2.0f * uy_;
    float evx = 2.0f * vx_, evy = 2.0f * vy_;
    float ruxP = __fdividef(1.0f, clamp_mag(eux));
    float ruyP = __fdividef(1.0f, clamp_mag(euy));
    float rvxP = __fdividef(1.0f, clamp_mag(evx));
    float rvyP = __fdividef(1.0f, clamp_mag(evy));
    // corners (CCW)
    float p0x = tx + ux_ + vx_, p0y = ty + uy_ + vy_;
    float p1x = tx - ux_ + vx_, p1y = ty - uy_ + vy_;
    float p2x = tx - ux_ - vx_, p2y = ty - uy_ - vy_;
    float p3x = tx + ux_ - vx_, p3y = ty + uy_ - vy_;

    float area2 = 0.0f, dDx = 0.0f, dDy = 0.0f;
    edge_piece(p0x, p0y, -eux, -euy, -ruxP, -ruyP, h2x, h2y, area2, dDx, dDy);
    edge_piece(p1x, p1y, -evx, -evy, -rvxP, -rvyP, h2x, h2y, area2, dDx, dDy);
    edge_piece(p2x, p2y,  eux,  euy,  ruxP,  ruyP, h2x, h2y, area2, dDx, dDy);
    edge_piece(p3x, p3y,  evx,  evy,  rvxP,  rvyP, h2x, h2y, area2, dDx, dDy);

    // Q in P's frame: u' = R^T·(h2x,0), v' = R^T·(0,h2y), o = -R^T·t
    float upx = h2x * cd,  upy = -h2x * sd;
    float vpx = h2y * sd,  vpy = h2y * cd;
    float ox  = -(fmaf(cd, tx,  sd * ty));
    float oy  = -(fmaf(-sd, tx, cd * ty));
    float equx = 2.0f * upx, equy = 2.0f * upy;
    float eqvx = 2.0f * vpx, eqvy = 2.0f * vpy;
    float ruxQ = __fdividef(1.0f, clamp_mag(equx));
    float ruyQ = __fdividef(1.0f, clamp_mag(equy));
    float rvxQ = __fdividef(1.0f, clamp_mag(eqvx));
    float rvyQ = __fdividef(1.0f, clamp_mag(eqvy));
    float q0x = ox + upx + vpx, q0y = oy + upy + vpy;
    float q1x = ox - upx + vpx, q1y = oy - upy + vpy;
    float q2x = ox - upx - vpx, q2y = oy - upy - vpy;
    float q3x = ox + upx - vpx, q3y = oy + upy - vpy;

    float Dx = 0.0f, Dy = 0.0f;
    edge_piece(q0x, q0y, -equx, -equy, -ruxQ, -ruyQ, h1x, h1y, area2, Dx, Dy);
    edge_piece(q1x, q1y, -eqvx, -eqvy, -rvxQ, -rvyQ, h1x, h1y, area2, Dx, Dy);
    edge_piece(q2x, q2y,  equx,  equy,  ruxQ,  ruyQ, h1x, h1y, area2, Dx, Dy);
    edge_piece(q3x, q3y,  eqvx,  eqvy,  rvxQ,  rvyQ, h1x, h1y, area2, Dx, Dy);

    // translation correction: cross(t, R·D)
    float RDx = fmaf(cd, Dx, -(sd * Dy));
    float RDy = fmaf(sd, Dx,   cd * Dy);
    area2 += fmaf(tx, RDy, -(ty * RDx));

    float inter = 0.5f * fabsf(area2);
    float uni = fmaxf(a1 + a2 - inter, 1e-6f);
    float iou = __fdividef(inter, uni);

    float target = (oh > 0) ? iou : 0.0f;
    float z  = __fdividef(1.0f, 1.0f + __expf(-ip));   // sigmoid
    float pt = __logf(1.0f + __expf(z)) - z * target;  // logaddexp(0,z) - z*target
    return pt * w;
}

__global__ __launch_bounds__(BLK)
void iou_pred_loss_kernel(const float* __restrict__ iou_preds,
                          const int*   __restrict__ one_hot,
                          const float* __restrict__ weights,
                          const float* __restrict__ anchors,
                          const float* __restrict__ box_preds,
                          const float* __restrict__ reg_targets,
                          float* __restrict__ out,
                          int N, int B)
{
    int tid   = threadIdx.x;
    int n_idx = blockIdx.x * BLK + tid;
    if (n_idx >= N) return;

    int yspan = gridDim.y;                 // = ceil(B/2)
    int b0 = blockIdx.y;
    int b1 = blockIdx.y + yspan;
    bool has2 = (b1 < B);
    size_t g0 = (size_t)b0 * N + n_idx;
    size_t g1 = (size_t)(has2 ? b1 : b0) * N + n_idx;

    // ---- issue ALL global loads up front (MLP) ----
    const float* an = anchors + (size_t)n_idx * 7;
    float xa = an[0], ya = an[1], dxa = an[3], dya = an[4], ra = an[6];

    const float* bpp0 = box_preds   + g0 * 7;
    const float* rtp0 = reg_targets + g0 * 7;
    const float* bpp1 = box_preds   + g1 * 7;
    const float* rtp1 = reg_targets + g1 * 7;
    float bp0[5] = {bpp0[0], bpp0[1], bpp0[3], bpp0[4], bpp0[6]};
    float rt0[5] = {rtp0[0], rtp0[1], rtp0[3], rtp0[4], rtp0[6]};
    float bp1[5] = {bpp1[0], bpp1[1], bpp1[3], bpp1[4], bpp1[6]};
    float rt1[5] = {rtp1[0], rtp1[1], rtp1[3], rtp1[4], rtp1[6]};
    float ip0 = iou_preds[g0], ip1 = iou_preds[g1];
    int   oh0 = one_hot[g0],   oh1 = one_hot[g1];
    float w0  = weights[g0],   w1  = weights[g1];

    float diag = sqrtf(fmaf(dxa, dxa, dya * dya));

    out[g0] = pair_loss(bp0, rt0, xa, ya, dxa, dya, ra, diag, ip0, oh0, w0);
    if (has2)
        out[g1] = pair_loss(bp1, rt1, xa, ya, dxa, dya, ra, diag, ip1, oh1, w1);
}

extern "C" void kernel_launch(void* const* d_in, const int* in_sizes, int n_in,
                              void* d_out, int out_size, void* d_ws, size_t ws_size,
                              hipStream_t stream) {
    const float* iou_preds   = (const float*)d_in[0];
    const int*   one_hot     = (const int*)  d_in[1];
    const float* weights     = (const float*)d_in[2];
    const float* anchors     = (const float*)d_in[3];
    const float* box_preds   = (const float*)d_in[4];
    const float* reg_targets = (const float*)d_in[5];
    float* out = (float*)d_out;

    int total = in_sizes[0];       // B*N
    int N     = in_sizes[3] / 7;   // anchor count
    int B     = total / N;

    dim3 grid((N + BLK - 1) / BLK, (B + 1) / 2);
    iou_pred_loss_kernel<<<grid, dim3(BLK), 0, stream>>>(
        iou_preds, one_hot, weights, anchors, box_preds, reg_targets,
        out, N, B);
}